// Round 18
// baseline (49.926 us; speedup 1.0000x reference)
//
#include <hip/hip_runtime.h>
#include <hip/hip_bf16.h>
#include <stdint.h>

#define N_ATOMS 131072
#define D_IN    128
#define D_HID   256
#define N_ELEM  4
#define NPAD    (N_ATOMS + N_ELEM * 64)   // 131328 slots max
#define K4_BLOCKS 512                      // 128q x 4e; 512 thr; 2 blocks/CU
#define HIST_BLOCKS 512                    // 512 x 256 atoms
#define K2_BLOCKS 512                      // permute blocks, 256 atoms each

typedef __attribute__((ext_vector_type(8))) short bf16x8;
typedef __attribute__((ext_vector_type(4))) float f32x4;
typedef unsigned long long ull;

// ws layout (bytes):
//   [0,       262144): W1t bf16 [4][256][128] (h-major, k contiguous)
//   [262272,  278656): bpart[4096] float (per-wave partials)
//   [278656,  278672): counts int4 (written by K2 block 0)
//   [295168,  303360): blockCounts[512][4] int
//   [1048576, 34668544): Xsorted bf16 [NPAD][128]
#define WS_BPART  262272
#define WS_CNT4   278656
#define WS_BCNT   295168
#define WS_XS     1048576

__device__ __forceinline__ unsigned short f2bf_rne(float f) {
    union { float f; unsigned u; } v; v.f = f;
    unsigned r = v.u + 0x7FFFu + ((v.u >> 16) & 1u);   // RNE
    return (unsigned short)(r >> 16);
}

__device__ __forceinline__ int4 wave_reduce4(int4 v) {
    #pragma unroll
    for (int off = 32; off; off >>= 1) {
        v.x += __shfl_xor(v.x, off);
        v.y += __shfl_xor(v.y, off);
        v.z += __shfl_xor(v.z, off);
        v.w += __shfl_xor(v.w, off);
    }
    return v;
}

__device__ __forceinline__ ull same_expert_mask(int e) {
    ull m0 = __ballot(e & 1);
    ull m1 = __ballot(e & 2);
    ull m = (e & 1) ? m0 : ~m0;
    return m & ((e & 2) ? m1 : ~m1);
}

// K1: blocks 0..31 transpose W1 -> W1t bf16; blocks 32..543 histogram (256 atoms each).
__global__ void tnn_k1_fused(const int* __restrict__ eid, int* __restrict__ bcnt,
                             const float* __restrict__ W1, unsigned short* __restrict__ W1t) {
    __shared__ float tile[64][65];
    __shared__ int lc[N_ELEM];
    int t = threadIdx.x;
    if (blockIdx.x < 32) {
        int b  = blockIdx.x;
        int e  = b >> 3;
        int k0 = ((b >> 2) & 1) * 64;
        int h0 = (b & 3) * 64;
        int cg = t & 15;
        int rr = t >> 4;
        const float* src = W1 + ((size_t)e * D_IN + k0) * D_HID + h0;
        #pragma unroll
        for (int j = 0; j < 4; ++j) {
            int row = rr + j * 16;
            f32x4 v = *(const f32x4*)(src + (size_t)row * D_HID + cg * 4);
            tile[row][cg * 4 + 0] = v[0];
            tile[row][cg * 4 + 1] = v[1];
            tile[row][cg * 4 + 2] = v[2];
            tile[row][cg * 4 + 3] = v[3];
        }
        __syncthreads();
        unsigned short* dst = W1t + ((size_t)e * D_HID + h0) * D_IN + k0;
        #pragma unroll
        for (int j = 0; j < 4; ++j) {
            int hrow = rr + j * 16;
            ushort4 o;
            o.x = f2bf_rne(tile[cg * 4 + 0][hrow]);
            o.y = f2bf_rne(tile[cg * 4 + 1][hrow]);
            o.z = f2bf_rne(tile[cg * 4 + 2][hrow]);
            o.w = f2bf_rne(tile[cg * 4 + 3][hrow]);
            *(ushort4*)(dst + (size_t)hrow * D_IN + cg * 4) = o;
        }
    } else {
        int hb = blockIdx.x - 32;
        int lane = t & 63;
        if (t < N_ELEM) lc[t] = 0;
        __syncthreads();
        int e = eid[hb * 256 + t];
        ull m = same_expert_mask(e);
        if (lane == __builtin_ctzll(m))
            atomicAdd(&lc[e], __popcll(m));           // 4 atomics/wave
        __syncthreads();
        if (t < N_ELEM) bcnt[hb * 4 + t] = lc[t];
    }
}

// K2: permute X -> Xsorted (bf16). Sequential f32 reads; stable ranks make the
// scattered writes 4 ascending contiguous streams per block. Block 0 also
// publishes counts to ws for K4/K5.
__global__ void tnn_k2_permute(const int* __restrict__ eid, const int* __restrict__ bcnt,
                               const float* __restrict__ X, unsigned short* __restrict__ Xs,
                               int* __restrict__ counts4) {
    __shared__ int ldsDest[256];
    __shared__ int base4[N_ELEM];
    __shared__ int lcsh[N_ELEM];
    int t = threadIdx.x;
    int b = blockIdx.x;
    int lane = t & 63;
    int wid  = t >> 6;
    if (t < N_ELEM) lcsh[t] = 0;

    if (wid == 0) {   // wave 0: scan 512 int4 counts -> totals + prefix for block b
        int4 tot = {0, 0, 0, 0};
        int4 pre = {0, 0, 0, 0};
        #pragma unroll
        for (int j = 0; j < 8; ++j) {
            int g = lane * 8 + j;
            int4 c = ((const int4*)bcnt)[g];
            tot.x += c.x; tot.y += c.y; tot.z += c.z; tot.w += c.w;
            if (g < b) { pre.x += c.x; pre.y += c.y; pre.z += c.z; pre.w += c.w; }
        }
        tot = wave_reduce4(tot);
        pre = wave_reduce4(pre);
        if (lane == 0) {
            int st0 = 0;
            int st1 = st0 + ((tot.x + 63) & ~63);
            int st2 = st1 + ((tot.y + 63) & ~63);
            int st3 = st2 + ((tot.z + 63) & ~63);
            base4[0] = st0 + pre.x;
            base4[1] = st1 + pre.y;
            base4[2] = st2 + pre.z;
            base4[3] = st3 + pre.w;
            if (b == 0) ((int4*)counts4)[0] = tot;
        }
    }
    __syncthreads();

    // rank: 1 atom/thread, ballot ranking (stable within wave, wave-batched cursor)
    {
        int e = eid[b * 256 + t];
        ull m = same_expert_mask(e);
        int f = __builtin_ctzll(m);
        ull below = (lane == 63) ? 0x7FFFFFFFFFFFFFFFULL : ((1ULL << lane) - 1);
        int rank = __popcll(m & below);
        int wbase = 0;
        if (lane == f) wbase = atomicAdd(&lcsh[e], __popcll(m));
        wbase = __shfl(wbase, f);
        ldsDest[t] = base4[e] + wbase + rank;
    }
    __syncthreads();

    // copy: pass p handles 8 rows; 32 threads per row -> fully coalesced
    int rloc = t >> 5;          // 0..7 row-in-pass
    int c32  = t & 31;          // 0..31 column group (4 floats)
    #pragma unroll 1
    for (int p = 0; p < 32; ++p) {
        int row  = p * 8 + rloc;
        int dest = ldsDest[row];
        f32x4 v = *(const f32x4*)(X + ((size_t)(b * 256 + row)) * D_IN + c32 * 4);
        ushort4 o;
        o.x = (unsigned short)(__float_as_uint(v[0]) >> 16);
        o.y = (unsigned short)(__float_as_uint(v[1]) >> 16);
        o.z = (unsigned short)(__float_as_uint(v[2]) >> 16);
        o.w = (unsigned short)(__float_as_uint(v[3]) >> 16);
        *(ushort4*)(Xs + (size_t)dest * D_IN + c32 * 4) = o;
    }
}

// nt-loop body (R11's proven shape), FULL-templated.
template<bool FULL>
__device__ __forceinline__ float nt_loop(const unsigned char* ldsB, const float2* ldsBW,
                                         unsigned ldso, const bf16x8 a0[4], const bf16x8 a1[4],
                                         int tb, int rend, int lk, int l15, float fnval) {
    const float C2 = 2.8853900817779268f;
    float partial = 0.f;
    #pragma unroll 1
    for (int nt = 0; nt < 16; ++nt) {
        const unsigned char* lb = ldsB + ldso + (unsigned)nt * 256u;
        bf16x8 cur0 = *(const bf16x8*)(lb);
        bf16x8 cur1 = *(const bf16x8*)(lb + 16384);
        bf16x8 cur2 = *(const bf16x8*)(lb + 32768);
        bf16x8 cur3 = *(const bf16x8*)(lb + 49152);
        float2 bw = ldsBW[nt * 16 + l15];

        f32x4 acc0 = {0.f, 0.f, 0.f, 0.f};
        f32x4 acc1 = {0.f, 0.f, 0.f, 0.f};
        acc0 = __builtin_amdgcn_mfma_f32_16x16x32_bf16(a0[0], cur0, acc0, 0, 0, 0);
        acc1 = __builtin_amdgcn_mfma_f32_16x16x32_bf16(a1[0], cur0, acc1, 0, 0, 0);
        acc0 = __builtin_amdgcn_mfma_f32_16x16x32_bf16(a0[1], cur1, acc0, 0, 0, 0);
        acc1 = __builtin_amdgcn_mfma_f32_16x16x32_bf16(a1[1], cur1, acc1, 0, 0, 0);
        acc0 = __builtin_amdgcn_mfma_f32_16x16x32_bf16(a0[2], cur2, acc0, 0, 0, 0);
        acc1 = __builtin_amdgcn_mfma_f32_16x16x32_bf16(a1[2], cur2, acc1, 0, 0, 0);
        acc0 = __builtin_amdgcn_mfma_f32_16x16x32_bf16(a0[3], cur3, acc0, 0, 0, 0);
        acc1 = __builtin_amdgcn_mfma_f32_16x16x32_bf16(a1[3], cur3, acc1, 0, 0, 0);

        // tanh(p) = 1 - 2/(exp2(C2*p)+1); sum w2*tanh = w2*(nval - 2*sum(rcp))
        float rs0 = 0.f, rs1 = 0.f;
        #pragma unroll
        for (int r = 0; r < 4; ++r) {
            float e0 = __builtin_amdgcn_exp2f(fmaf(C2, acc0[r], bw.x));
            float e1 = __builtin_amdgcn_exp2f(fmaf(C2, acc1[r], bw.x));
            float rc0 = __builtin_amdgcn_rcpf(e0 + 1.f);
            float rc1 = __builtin_amdgcn_rcpf(e1 + 1.f);
            if (!FULL) {
                rc0 = (tb + lk * 4 + r      < rend) ? rc0 : 0.f;
                rc1 = (tb + 16 + lk * 4 + r < rend) ? rc1 : 0.f;
            }
            rs0 += rc0;
            rs1 += rc1;
        }
        partial = fmaf(bw.y, fmaf(-2.f, rs0 + rs1, fnval), partial);
    }
    return partial;
}

// K4: 512 blocks x 512 thr (2 blocks/CU, (512,4) proven no-crunch). Full-expert
// W1t in LDS (64 KB k-major, conflict-free). Wave = 32-atom tile read
// SEQUENTIALLY from Xs (bf16, no index, no convert); the 8 A-loads are issued
// BEFORE the B-staging barrier so they land during staging -> no exposed latency.
__global__ __launch_bounds__(512, 4) void tnn_k4_mlp(
        const unsigned short* __restrict__ Xs, const int* __restrict__ counts4,
        const unsigned short* __restrict__ W1t, const float* __restrict__ b1,
        const float* __restrict__ W2, float* __restrict__ bpart) {
    __shared__ unsigned char ldsB[65536];   // [16 kblk][256 h][16 B]  (k-major)
    __shared__ float2 ldsBW[256];           // {b1*C2, w2} per h
    const float C2 = 2.8853900817779268f;

    int t = threadIdx.x;
    int wid  = t >> 6;                       // 0..7
    int lane = t & 63;
    int l15  = lane & 15;
    int lk   = lane >> 4;
    int e    = blockIdx.x & 3;
    int q    = blockIdx.x >> 2;              // 0..127

    int4 cnt = *(const int4*)counts4;
    int cnts[4] = {cnt.x, cnt.y, cnt.z, cnt.w};
    int st[5];
    st[0] = 0;
    #pragma unroll
    for (int i = 0; i < 4; ++i) st[i + 1] = st[i] + ((cnts[i] + 63) & ~63);
    int bstart = st[e];
    int rend   = bstart + cnts[e];
    int Te     = (st[e + 1] - bstart) >> 5;       // 32-atom tiles

    // ---- hoist first tile's A-loads (sequential bf16) BEFORE staging ----
    int tt0 = q * 8 + wid;
    bf16x8 a0[4], a1[4];
    bool have0 = (tt0 < Te);
    int tb0 = bstart + tt0 * 32;
    if (have0) {
        const unsigned short* x0 = Xs + (size_t)(tb0 + l15) * D_IN + lk * 8;
        const unsigned short* x1 = Xs + (size_t)(tb0 + 16 + l15) * D_IN + lk * 8;
        #pragma unroll
        for (int ks = 0; ks < 4; ++ks) a0[ks] = *(const bf16x8*)(x0 + ks * 32);
        #pragma unroll
        for (int ks = 0; ks < 4; ++ks) a1[ks] = *(const bf16x8*)(x1 + ks * 32);
    }

    // ---- stage B (k-major): thread t = (h-row t>>1, k-half t&1) ----
    {
        int hrow  = t >> 1;
        int khalf = t & 1;
        const unsigned short* src = W1t + ((size_t)e * D_HID + hrow) * D_IN + khalf * 64;
        #pragma unroll
        for (int jj = 0; jj < 8; ++jj) {
            bf16x8 v = *(const bf16x8*)(src + jj * 8);
            *(bf16x8*)(ldsB + (khalf * 8 + jj) * 4096 + hrow * 16) = v;
        }
        if (t < 256) ldsBW[t] = make_float2(b1[e * D_HID + t] * C2, W2[e * D_HID + t]);
    }
    __syncthreads();

    unsigned ldso = (unsigned)lk * 4096u + (unsigned)l15 * 16u;

    float partial = 0.f;
    if (have0) {
        bool full = (tb0 + 32 <= rend);
        if (full) {
            partial += nt_loop<true >(ldsB, ldsBW, ldso, a0, a1, tb0, rend, lk, l15, 8.f);
        } else {
            int nv = 0;
            #pragma unroll
            for (int m = 0; m < 2; ++m)
                #pragma unroll
                for (int r = 0; r < 4; ++r)
                    nv += (tb0 + m * 16 + lk * 4 + r < rend) ? 1 : 0;
            partial += nt_loop<false>(ldsB, ldsBW, ldso, a0, a1, tb0, rend, lk, l15, (float)nv);
        }
    }
    // rare tail: Te may slightly exceed 1024 tiles (expert imbalance)
    #pragma unroll 1
    for (int tt = tt0 + 1024; tt < Te; tt += 1024) {
        int tb = bstart + tt * 32;
        const unsigned short* x0 = Xs + (size_t)(tb + l15) * D_IN + lk * 8;
        const unsigned short* x1 = Xs + (size_t)(tb + 16 + l15) * D_IN + lk * 8;
        #pragma unroll
        for (int ks = 0; ks < 4; ++ks) a0[ks] = *(const bf16x8*)(x0 + ks * 32);
        #pragma unroll
        for (int ks = 0; ks < 4; ++ks) a1[ks] = *(const bf16x8*)(x1 + ks * 32);
        bool full = (tb + 32 <= rend);
        if (full) {
            partial += nt_loop<true >(ldsB, ldsBW, ldso, a0, a1, tb, rend, lk, l15, 8.f);
        } else {
            int nv = 0;
            #pragma unroll
            for (int m = 0; m < 2; ++m)
                #pragma unroll
                for (int r = 0; r < 4; ++r)
                    nv += (tb + m * 16 + lk * 4 + r < rend) ? 1 : 0;
            partial += nt_loop<false>(ldsB, ldsBW, ldso, a0, a1, tb, rend, lk, l15, (float)nv);
        }
    }

    #pragma unroll
    for (int off = 32; off; off >>= 1)
        partial += __shfl_down(partial, off);
    if (lane == 0) bpart[blockIdx.x * 8 + wid] = partial;   // plain store
}

// K5: reduce 4096 per-wave partials + analytic bias from published counts.
__global__ void tnn_k5_reduce(const float* __restrict__ bpart, const int* __restrict__ counts4,
                              const float* __restrict__ b2, float* __restrict__ out) {
    __shared__ float r[4];
    int t = threadIdx.x;
    float s = 0.f;
    #pragma unroll
    for (int j = 0; j < 16; ++j) s += bpart[j * 256 + t];
    #pragma unroll
    for (int off = 32; off; off >>= 1)
        s += __shfl_down(s, off);
    if ((t & 63) == 0) r[t >> 6] = s;
    __syncthreads();
    if (t == 0) {
        int4 tot = *(const int4*)counts4;
        float acc = r[0] + r[1] + r[2] + r[3];
        acc += (float)tot.x * b2[0];
        acc += (float)tot.y * b2[1];
        acc += (float)tot.z * b2[2];
        acc += (float)tot.w * b2[3];
        out[0] = acc;
    }
}

extern "C" void kernel_launch(void* const* d_in, const int* in_sizes, int n_in,
                              void* d_out, int out_size, void* d_ws, size_t ws_size,
                              hipStream_t stream) {
    const float* X   = (const float*)d_in[0];
    const int*   eid = (const int*)  d_in[1];
    const float* W1  = (const float*)d_in[2];
    const float* b1  = (const float*)d_in[3];
    const float* W2  = (const float*)d_in[4];
    const float* b2  = (const float*)d_in[5];
    float* out = (float*)d_out;

    char* ws = (char*)d_ws;
    unsigned short* W1t = (unsigned short*)ws;
    float*          bpart   = (float*)         (ws + WS_BPART);
    int*            counts4 = (int*)           (ws + WS_CNT4);
    int*            bcnt    = (int*)           (ws + WS_BCNT);
    unsigned short* Xs      = (unsigned short*)(ws + WS_XS);

    hipLaunchKernelGGL(tnn_k1_fused,   dim3(32 + HIST_BLOCKS), dim3(256), 0, stream,
                       eid, bcnt, W1, W1t);
    hipLaunchKernelGGL(tnn_k2_permute, dim3(K2_BLOCKS),        dim3(256), 0, stream,
                       eid, bcnt, X, Xs, counts4);
    hipLaunchKernelGGL(tnn_k4_mlp,     dim3(K4_BLOCKS),        dim3(512), 0, stream,
                       Xs, counts4, W1t, b1, W2, bpart);
    hipLaunchKernelGGL(tnn_k5_reduce,  dim3(1),                dim3(256), 0, stream,
                       bpart, counts4, b2, out);
}